// Round 1
// baseline (635.685 us; speedup 1.0000x reference)
//
#include <hip/hip_runtime.h>
#include <cfloat>

#define NTOK (64 * 4096)   // 262144 tokens
#define HID  128
#define NE   64
#define TK   6
#define TPB  128           // tokens per block-iteration (LDS tile rows)
#define TPW  32            // tokens per wave per iteration
#define GRID 1024
#define ITERS 2            // GRID * ITERS * TPB == NTOK exactly

__global__ void gate_kernel(const float* __restrict__ X,
                            const float* __restrict__ W,
                            float* __restrict__ oidx,
                            float* __restrict__ ow,
                            float* __restrict__ Pi_g,
                            unsigned int* __restrict__ cnt_g)
{
    // swizzled logit tile: (t,e) stored at t*64 + ((e + t) & 63)  -> conflict-free
    __shared__ float        Lt[TPB * NE];     // 32 KB
    __shared__ float        mz[TPB * 2];      // (m, 1/Z) per token
    __shared__ float        Pi_s[NE];
    __shared__ unsigned int cnt_s[NE];

    const int tid  = threadIdx.x;
    const int lane = tid & 63;
    const int wid  = __builtin_amdgcn_readfirstlane(tid >> 6);

    if (tid < NE) { Pi_s[tid] = 0.0f; cnt_s[tid] = 0u; }

    // Each lane = one expert; keep its W row resident in VGPRs for the whole kernel.
    float wreg[HID];
    {
        const float4* wr = (const float4*)(W + lane * HID);
#pragma unroll
        for (int i = 0; i < HID / 4; ++i) {
            float4 v = wr[i];
            wreg[4*i+0] = v.x; wreg[4*i+1] = v.y;
            wreg[4*i+2] = v.z; wreg[4*i+3] = v.w;
        }
    }

    float pi_acc = 0.0f;   // per-lane (=expert) softmax-prob partial sum

    for (int it = 0; it < ITERS; ++it) {
        __syncthreads();   // protect Lt reuse across iterations
        const int blk_base = (blockIdx.x * ITERS + it) * TPB;
        const int wbase    = wid * TPW;

        // ---- GEMM: lane = expert, x via wave-uniform (scalar) loads ----
        for (int sb = 0; sb < TPW / 4; ++sb) {
            const int lt0 = wbase + sb * 4;
            const float* xp = X + (size_t)(blk_base + lt0) * HID;  // wave-uniform
            float a0 = 0.f, a1 = 0.f, a2 = 0.f, a3 = 0.f;
#pragma unroll
            for (int k = 0; k < HID; ++k) {
                const float wv = wreg[k];
                a0 = fmaf(xp[k          ], wv, a0);
                a1 = fmaf(xp[k +   HID  ], wv, a1);
                a2 = fmaf(xp[k + 2*HID  ], wv, a2);
                a3 = fmaf(xp[k + 3*HID  ], wv, a3);
            }
            Lt[(lt0+0)*NE + ((lane + lt0+0) & 63)] = a0;
            Lt[(lt0+1)*NE + ((lane + lt0+1) & 63)] = a1;
            Lt[(lt0+2)*NE + ((lane + lt0+2) & 63)] = a2;
            Lt[(lt0+3)*NE + ((lane + lt0+3) & 63)] = a3;
        }
        __syncthreads();

        // ---- top-6 + weights: one thread per token (threads 0..127) ----
        if (tid < TPB) {
            const int t = tid;
            float tv[TK];
            int   tix[TK];
#pragma unroll
            for (int q = 0; q < TK; ++q) { tv[q] = -FLT_MAX; tix[q] = 0; }

#pragma unroll 4
            for (int e = 0; e < NE; ++e) {
                const float v = Lt[t*NE + ((e + t) & 63)];
                if (v > tv[TK-1]) {
                    tv[TK-1] = v; tix[TK-1] = e;
#pragma unroll
                    for (int q = TK-1; q > 0; --q) {
                        const bool sw = tv[q] > tv[q-1];   // strict: stable tie order
                        const float fv = sw ? tv[q-1] : tv[q];
                        const float gv = sw ? tv[q]   : tv[q-1];
                        const int   fi = sw ? tix[q-1] : tix[q];
                        const int   gi = sw ? tix[q]   : tix[q-1];
                        tv[q] = fv; tv[q-1] = gv; tix[q] = fi; tix[q-1] = gi;
                    }
                }
            }

            const float m = tv[0];
            float ex[TK];
            float s = 0.0f;
#pragma unroll
            for (int q = 0; q < TK; ++q) { ex[q] = __expf(tv[q] - m); s += ex[q]; }
            const float rs = 1.0f / (s + 1e-20f);

            const size_t gt = (size_t)(blk_base + t);
#pragma unroll
            for (int q = 0; q < TK; ++q) {
                oidx[gt*TK + q] = (float)tix[q];
                ow  [gt*TK + q] = ex[q] * rs;
            }
#pragma unroll
            for (int q = 0; q < TK; ++q) atomicAdd(&cnt_s[tix[q]], 1u);

            // full softmax denominator for the aux-loss Pi accumulation
            float Z = 0.0f;
#pragma unroll 4
            for (int e = 0; e < NE; ++e) {
                const float v = Lt[t*NE + ((e + t) & 63)];
                Z += __expf(v - m);
            }
            mz[t*2]     = m;
            mz[t*2 + 1] = 1.0f / Z;
        }
        __syncthreads();

        // ---- Pi: lane = expert, over this wave's tokens ----
        for (int q = 0; q < TPW; ++q) {
            const int lt  = wbase + q;
            const float m  = mz[lt*2];
            const float rz = mz[lt*2 + 1];
            const float v  = Lt[lt*NE + ((lane + lt) & 63)];
            pi_acc += __expf(v - m) * rz;
        }
    }

    __syncthreads();
    atomicAdd(&Pi_s[lane], pi_acc);
    __syncthreads();
    if (tid < NE) {
        atomicAdd(&Pi_g[tid], Pi_s[tid]);
        atomicAdd(&cnt_g[tid], cnt_s[tid]);
    }
}

__global__ void aux_kernel(const float* __restrict__ Pi_g,
                           const unsigned int* __restrict__ cnt_g,
                           float* __restrict__ out_aux)
{
    const int e = threadIdx.x;   // 64 threads
    const float Pi = Pi_g[e] * (1.0f / (float)NTOK);
    const float ce = (float)cnt_g[e] * (1.0f / (float)(NTOK * TK));
    float v = Pi * ce * (float)NE;
#pragma unroll
    for (int off = 32; off > 0; off >>= 1) v += __shfl_down(v, off);
    if (e == 0) out_aux[0] = v * 1.0e-3f;
}

extern "C" void kernel_launch(void* const* d_in, const int* in_sizes, int n_in,
                              void* d_out, int out_size, void* d_ws, size_t ws_size,
                              hipStream_t stream) {
    const float* X = (const float*)d_in[0];
    const float* W = (const float*)d_in[1];

    float* out  = (float*)d_out;
    float* oidx = out;                          // N*6 indices (as float)
    float* ow   = out + (size_t)NTOK * TK;      // N*6 weights
    float* aux  = out + (size_t)NTOK * TK * 2;  // 1 scalar

    float*        Pi_g  = (float*)d_ws;
    unsigned int* cnt_g = (unsigned int*)((char*)d_ws + 256);

    hipMemsetAsync(d_ws, 0, 512, stream);
    gate_kernel<<<GRID, 256, 0, stream>>>(X, W, oidx, ow, Pi_g, cnt_g);
    aux_kernel<<<1, 64, 0, stream>>>(Pi_g, cnt_g, aux);
}

// Round 2
// 308.308 us; speedup vs baseline: 2.0619x; 2.0619x over previous
//
#include <hip/hip_runtime.h>
#include <cfloat>

#define NTOK (64 * 4096)   // 262144 tokens
#define HID  128
#define NE   64
#define TK   6
#define CHUNK 32           // k-chunk of x held in VGPRs (one full 128B line/row)
#define NCH  (HID / CHUNK) // 4
#define EG   4             // experts per inner group (4 independent FMA chains)
#define NEG  (NE / EG)     // 16
#define KS   16            // k sub-tile per scalar W load group (4x16 floats live in SGPRs)

__global__ __launch_bounds__(256, 4)
void gate_kernel(const float* __restrict__ X,
                 const float* __restrict__ W,
                 float* __restrict__ oidx,
                 float* __restrict__ ow,
                 float* __restrict__ Pi_g,
                 unsigned int* __restrict__ cnt_g)
{
    __shared__ float        Pi_s[NE];
    __shared__ unsigned int cnt_s[NE];

    const int tid  = threadIdx.x;
    const int lane = tid & 63;

    if (tid < NE) { Pi_s[tid] = 0.0f; cnt_s[tid] = 0u; }
    __syncthreads();

    const int token = blockIdx.x * 256 + tid;      // grid covers NTOK exactly
    const float* xrow = X + (size_t)token * HID;

    float acc[NE];
#pragma unroll
    for (int e = 0; e < NE; ++e) acc[e] = 0.0f;

    // ---- logits: acc[e] = x . W[e]  (x per-lane VGPR, W via uniform scalar loads)
    for (int c = 0; c < NCH; ++c) {
        float x[CHUNK];
        const float4* xp = (const float4*)(xrow + c * CHUNK);
#pragma unroll
        for (int i = 0; i < CHUNK / 4; ++i) {
            float4 v = xp[i];
            x[4*i+0] = v.x; x[4*i+1] = v.y; x[4*i+2] = v.z; x[4*i+3] = v.w;
        }
        const float* wb = W + c * CHUNK;           // lane-uniform base
#pragma unroll
        for (int eg = 0; eg < NEG; ++eg) {
#pragma unroll
            for (int ks = 0; ks < CHUNK / KS; ++ks) {
#pragma unroll
                for (int k = 0; k < KS; ++k) {
#pragma unroll
                    for (int e = 0; e < EG; ++e) {
                        const int ee = eg * EG + e;
                        acc[ee] = fmaf(x[ks*KS + k], wb[ee * HID + ks*KS + k], acc[ee]);
                    }
                }
            }
        }
    }

    // ---- top-6 (branchless insertion, strict > keeps jax stable tie order)
    float tv[TK];
    int   ti[TK];
#pragma unroll
    for (int q = 0; q < TK; ++q) { tv[q] = -FLT_MAX; ti[q] = 0; }

#pragma unroll
    for (int e = 0; e < NE; ++e) {
        float m = acc[e];
        int   mi = e;
#pragma unroll
        for (int q = 0; q < TK; ++q) {
            const bool  c  = m > tv[q];
            const float nt = c ? m     : tv[q];
            const float nm = c ? tv[q] : m;
            const int   ni = c ? mi    : ti[q];
            const int   nj = c ? ti[q] : mi;
            tv[q] = nt; m = nm; ti[q] = ni; mi = nj;
        }
    }

    // ---- weights (renormalized top-6 softmax; Z cancels, epsilon negligible)
    const float mx = tv[0];
    float ex[TK];
    float s = 0.0f;
#pragma unroll
    for (int q = 0; q < TK; ++q) { ex[q] = __expf(tv[q] - mx); s += ex[q]; }
    const float rs = 1.0f / (s + 1e-20f);

    {
        const size_t gt = (size_t)token * TK;
        float2* ip = (float2*)(oidx + gt);
        float2* wp = (float2*)(ow + gt);
        ip[0] = make_float2((float)ti[0], (float)ti[1]);
        ip[1] = make_float2((float)ti[2], (float)ti[3]);
        ip[2] = make_float2((float)ti[4], (float)ti[5]);
        wp[0] = make_float2(ex[0]*rs, ex[1]*rs);
        wp[1] = make_float2(ex[2]*rs, ex[3]*rs);
        wp[2] = make_float2(ex[4]*rs, ex[5]*rs);
    }

#pragma unroll
    for (int q = 0; q < TK; ++q) atomicAdd(&cnt_s[ti[q]], 1u);

    // ---- full softmax for aux-loss Pi; reuse acc[] for the exps
    float Z = 0.0f;
#pragma unroll
    for (int e = 0; e < NE; ++e) { acc[e] = __expf(acc[e] - mx); Z += acc[e]; }
    const float rz = 1.0f / Z;

    // per-expert butterfly reduce across the wave's 64 tokens; lane e keeps expert e
    float pi_acc = 0.0f;
#pragma unroll
    for (int e = 0; e < NE; ++e) {
        float p = acc[e] * rz;
        p += __shfl_xor(p, 1);
        p += __shfl_xor(p, 2);
        p += __shfl_xor(p, 4);
        p += __shfl_xor(p, 8);
        p += __shfl_xor(p, 16);
        p += __shfl_xor(p, 32);
        pi_acc += (lane == e) ? p : 0.0f;
    }
    atomicAdd(&Pi_s[lane], pi_acc);

    __syncthreads();
    if (tid < NE) {
        atomicAdd(&Pi_g[tid], Pi_s[tid]);
        atomicAdd(&cnt_g[tid], cnt_s[tid]);
    }
}

__global__ void aux_kernel(const float* __restrict__ Pi_g,
                           const unsigned int* __restrict__ cnt_g,
                           float* __restrict__ out_aux)
{
    const int e = threadIdx.x;   // 64 threads
    const float Pi = Pi_g[e] * (1.0f / (float)NTOK);
    const float ce = (float)cnt_g[e] * (1.0f / (float)(NTOK * TK));
    float v = Pi * ce * (float)NE;
#pragma unroll
    for (int off = 32; off > 0; off >>= 1) v += __shfl_down(v, off);
    if (e == 0) out_aux[0] = v * 1.0e-3f;
}

extern "C" void kernel_launch(void* const* d_in, const int* in_sizes, int n_in,
                              void* d_out, int out_size, void* d_ws, size_t ws_size,
                              hipStream_t stream) {
    const float* X = (const float*)d_in[0];
    const float* W = (const float*)d_in[1];

    float* out  = (float*)d_out;
    float* oidx = out;                          // N*6 indices (as float)
    float* ow   = out + (size_t)NTOK * TK;      // N*6 weights
    float* aux  = out + (size_t)NTOK * TK * 2;  // 1 scalar

    float*        Pi_g  = (float*)d_ws;
    unsigned int* cnt_g = (unsigned int*)((char*)d_ws + 256);

    hipMemsetAsync(d_ws, 0, 512, stream);
    gate_kernel<<<NTOK / 256, 256, 0, stream>>>(X, W, oidx, ow, Pi_g, cnt_g);
    aux_kernel<<<1, 64, 0, stream>>>(Pi_g, cnt_g, aux);
}